// Round 18
// baseline (470.019 us; speedup 1.0000x reference)
//
#include <hip/hip_runtime.h>
#include <math.h>

#define HIDDEN 128
#define NEG_SLOPE 0.2f

typedef unsigned short u16;
typedef __attribute__((ext_vector_type(8))) short bf16x8;
typedef __attribute__((ext_vector_type(4))) float f32x4;

__device__ __forceinline__ u16 f2bf(float f) {
    unsigned u = __float_as_uint(f);
    unsigned r = (u + 0x7FFFu + ((u >> 16) & 1u)) >> 16;   // round-nearest-even
    return (u16)r;
}
__device__ __forceinline__ float bf2f(u16 u) {
    return __uint_as_float((unsigned)u << 16);
}
__device__ __forceinline__ unsigned pack2(float a, float b) {
    return (unsigned)f2bf(a) | ((unsigned)f2bf(b) << 16);
}
__device__ __forceinline__ float lo16f(unsigned v) { return bf2f((u16)v); }
__device__ __forceinline__ float hi16f(unsigned v) { return bf2f((u16)(v >> 16)); }

// ============ fp32->bf16 weight conversion + cnt zeroing (one dispatch) =======
struct WPtrs { const float* p[7]; };
__global__ void convw_zero_kernel(WPtrs wp, unsigned* __restrict__ wb, int totalPairs,
                                  int* __restrict__ cnt, int N) {
    int i = blockIdx.x * blockDim.x + threadIdx.x;
    if (i < N) cnt[i] = 0;
    if (i < totalPairs) {
        int e = i * 2;
        int seg, off;
        if (e < 98304) { seg = e >> 14; off = e & 16383; }
        else           { seg = 6;       off = e - 98304; }
        const float* s = wp.p[seg];
        wb[i] = pack2(s[off], s[off + 1]);
    }
}

// ============ encoder: A-frags computed in registers (no Xs LDS) ==============
// One block = 64 nodes. h1 values are closed-form per element, so each MFMA
// lane computes its own A-fragment. Two passes (item/con) share Ws LDS.
// [R17 lesson: fusing lin0 in here via an LDS D->A tile costs 2.5M bank
//  conflicts + occupancy drop -> slower than separate kernels. Keep split.]
__global__ __launch_bounds__(256) void encoder_kernel(
        const float* __restrict__ x, const int* __restrict__ types,
        const float* __restrict__ ew1, const float* __restrict__ eb1,
        const float* __restrict__ cw1, const float* __restrict__ cb1,
        const u16* __restrict__ wb_ew2, const u16* __restrict__ wb_cw2,
        const float* __restrict__ eb2, const float* __restrict__ cb2,
        u16* __restrict__ out, int N) {
    __shared__ u16 Ws[128 * 136];
    __shared__ float xsh[128];
    __shared__ float w1sh[640];   // ew1(256) eb1(128) cw1(128) cb1(128)
    const int tid = threadIdx.x;
    const int n0 = blockIdx.x * 64;

    if (tid < 128) {
        int n = n0 + (tid >> 1);
        xsh[tid] = (n < N) ? x[2 * n + (tid & 1)] : 0.f;
    }
    if (tid < 256) w1sh[tid] = ew1[tid];
    if (tid < 128) { w1sh[256 + tid] = eb1[tid]; w1sh[384 + tid] = cw1[tid];
                     w1sh[512 + tid] = cb1[tid]; }
#pragma unroll
    for (int r = 0; r < 8; r++) {
        int j = r * 256 + tid;
        int row = j >> 4, c8 = (j & 15) << 3;
        *(uint4*)&Ws[row * 136 + c8] = *(const uint4*)&wb_ew2[(size_t)row * 128 + c8];
    }
    __syncthreads();

    const int w = tid >> 6, lane = tid & 63;
    const int qd = lane >> 4, lr = lane & 15;
    const int arow = w * 16 + lr;
    const float x0 = xsh[2 * arow], x1 = xsh[2 * arow + 1];

    f32x4 acc_i[8], acc_c[8];
#pragma unroll
    for (int j = 0; j < 8; j++) acc_i[j] = (f32x4){0.f, 0.f, 0.f, 0.f};

#pragma unroll
    for (int k = 0; k < 4; k++) {
        bf16x8 a;
#pragma unroll
        for (int j = 0; j < 8; j++) {
            int t = k * 32 + qd * 8 + j;
            float v = fmaxf(w1sh[2 * t] * x0 + w1sh[2 * t + 1] * x1 + w1sh[256 + t], 0.f);
            a[j] = (short)f2bf(v);
        }
#pragma unroll
        for (int j = 0; j < 8; j++) {
            bf16x8 b = *(const bf16x8*)&Ws[(j * 16 + lr) * 136 + k * 32 + qd * 8];
            acc_i[j] = __builtin_amdgcn_mfma_f32_16x16x32_bf16(a, b, acc_i[j], 0, 0, 0);
        }
    }
    __syncthreads();

#pragma unroll
    for (int r = 0; r < 8; r++) {
        int j = r * 256 + tid;
        int rw = j >> 4, c8 = (j & 15) << 3;
        *(uint4*)&Ws[rw * 136 + c8] = *(const uint4*)&wb_cw2[(size_t)rw * 128 + c8];
    }
    __syncthreads();

#pragma unroll
    for (int j = 0; j < 8; j++) acc_c[j] = (f32x4){0.f, 0.f, 0.f, 0.f};
#pragma unroll
    for (int k = 0; k < 4; k++) {
        bf16x8 a;
#pragma unroll
        for (int j = 0; j < 8; j++) {
            int t = k * 32 + qd * 8 + j;
            float v = fmaxf(w1sh[384 + t] * x0 + w1sh[512 + t], 0.f);
            a[j] = (short)f2bf(v);
        }
#pragma unroll
        for (int j = 0; j < 8; j++) {
            bf16x8 b = *(const bf16x8*)&Ws[(j * 16 + lr) * 136 + k * 32 + qd * 8];
            acc_c[j] = __builtin_amdgcn_mfma_f32_16x16x32_bf16(a, b, acc_c[j], 0, 0, 0);
        }
    }

    // epilogue: per-row type select  (D: col=j*16+lr, row=n0+w*16+qd*4+r)
#pragma unroll
    for (int r = 0; r < 4; r++) {
        int orow = n0 + w * 16 + qd * 4 + r;
        if (orow >= N) continue;
        int ty = types[orow];
#pragma unroll
        for (int j = 0; j < 8; j++) {
            int col = j * 16 + lr;
            float v;
            if (ty == 0)      v = fmaxf(acc_i[j][r] + eb2[col], 0.f);
            else if (ty == 1) v = fmaxf(acc_c[j][r] + cb2[col], 0.f);
            else              v = 0.f;
            out[(size_t)orow * HIDDEN + col] = f2bf(v);
        }
    }
}

// ============ hl GEMM: X @ lin^T + attention dots =============================
template <int DH>
__global__ __launch_bounds__(256) void gemm_hl_kernel(
        const u16* __restrict__ X, const u16* __restrict__ Wb,
        const float* __restrict__ att_s, const float* __restrict__ att_d,
        u16* __restrict__ hl, float* __restrict__ a_s, float* __restrict__ a_d,
        int N) {
    __shared__ u16 Xs[64 * 136];
    __shared__ u16 Ws[128 * 136];
    const int tid = threadIdx.x;
    const int n0 = blockIdx.x * 64;

#pragma unroll
    for (int r = 0; r < 4; r++) {
        int j = r * 256 + tid;
        int row = j >> 4, c8 = (j & 15) << 3;
        int n = n0 + row;
        uint4 v = make_uint4(0u, 0u, 0u, 0u);
        if (n < N) v = *(const uint4*)&X[(size_t)n * 128 + c8];
        *(uint4*)&Xs[row * 136 + c8] = v;
    }
#pragma unroll
    for (int r = 0; r < 8; r++) {
        int j = r * 256 + tid;
        int row = j >> 4, c8 = (j & 15) << 3;
        *(uint4*)&Ws[row * 136 + c8] = *(const uint4*)&Wb[(size_t)row * 128 + c8];
    }
    __syncthreads();

    const int w = tid >> 6, lane = tid & 63;
    const int qd = lane >> 4, lr = lane & 15;

    f32x4 acc[8];
#pragma unroll
    for (int j = 0; j < 8; j++) acc[j] = (f32x4){0.f, 0.f, 0.f, 0.f};
#pragma unroll
    for (int k = 0; k < 4; k++) {
        bf16x8 a = *(const bf16x8*)&Xs[(w * 16 + lr) * 136 + k * 32 + qd * 8];
#pragma unroll
        for (int j = 0; j < 8; j++) {
            bf16x8 b = *(const bf16x8*)&Ws[(j * 16 + lr) * 136 + k * 32 + qd * 8];
            acc[j] = __builtin_amdgcn_mfma_f32_16x16x32_bf16(a, b, acc[j], 0, 0, 0);
        }
    }

    constexpr int NH = (DH == 4) ? 4 : 1;
    float sp[NH][4], dp[NH][4];
#pragma unroll
    for (int h = 0; h < NH; h++)
#pragma unroll
        for (int r = 0; r < 4; r++) { sp[h][r] = 0.f; dp[h][r] = 0.f; }
#pragma unroll
    for (int j = 0; j < 8; j++) {
        int col = j * 16 + lr;
        float as_ = att_s[col], ad_ = att_d[col];
        int h = (DH == 4) ? (j >> 1) : 0;
#pragma unroll
        for (int r = 0; r < 4; r++) {
            sp[h][r] += acc[j][r] * as_;
            dp[h][r] += acc[j][r] * ad_;
        }
    }
#pragma unroll
    for (int m = 1; m < 16; m <<= 1)
#pragma unroll
        for (int h = 0; h < NH; h++)
#pragma unroll
            for (int r = 0; r < 4; r++) {
                sp[h][r] += __shfl_xor(sp[h][r], m, 64);
                dp[h][r] += __shfl_xor(dp[h][r], m, 64);
            }
    if (lr == 0) {
#pragma unroll
        for (int r = 0; r < 4; r++) {
            int row = n0 + w * 16 + qd * 4 + r;
            if (row < N) {
#pragma unroll
                for (int h = 0; h < NH; h++) {
                    a_s[row * DH + h] = sp[h][r];
                    a_d[row * DH + h] = dp[h][r];
                }
            }
        }
    }
#pragma unroll
    for (int r = 0; r < 4; r++) {
        int row = n0 + w * 16 + qd * 4 + r;
        if (row >= N) continue;
#pragma unroll
        for (int j = 0; j < 8; j++)
            hl[(size_t)row * 128 + j * 16 + lr] = f2bf(acc[j][r]);
    }
}

// ============ FUSED decoder: d1 GEMM -> d2 GEMM -> dot/sigmoid/mask ===========
__global__ __launch_bounds__(256) void dec_kernel(
        const u16* __restrict__ X, const int* __restrict__ types,
        const u16* __restrict__ wb_dw1, const float* __restrict__ db1,
        const u16* __restrict__ wb_dw2, const float* __restrict__ db2,
        const float* __restrict__ dw3, const float* __restrict__ db3,
        float* __restrict__ fout, int N) {
    __shared__ u16 Xs[64 * 136];
    __shared__ u16 Ws[128 * 136];
    const int tid = threadIdx.x;
    const int n0 = blockIdx.x * 64;

#pragma unroll
    for (int r = 0; r < 4; r++) {
        int j = r * 256 + tid;
        int row = j >> 4, c8 = (j & 15) << 3;
        int n = n0 + row;
        uint4 v = make_uint4(0u, 0u, 0u, 0u);
        if (n < N) v = *(const uint4*)&X[(size_t)n * 128 + c8];
        *(uint4*)&Xs[row * 136 + c8] = v;
    }
#pragma unroll
    for (int r = 0; r < 8; r++) {
        int j = r * 256 + tid;
        int row = j >> 4, c8 = (j & 15) << 3;
        *(uint4*)&Ws[row * 136 + c8] = *(const uint4*)&wb_dw1[(size_t)row * 128 + c8];
    }
    __syncthreads();

    const int w = tid >> 6, lane = tid & 63;
    const int qd = lane >> 4, lr = lane & 15;

    f32x4 acc[8];
#pragma unroll
    for (int j = 0; j < 8; j++) acc[j] = (f32x4){0.f, 0.f, 0.f, 0.f};
#pragma unroll
    for (int k = 0; k < 4; k++) {
        bf16x8 a = *(const bf16x8*)&Xs[(w * 16 + lr) * 136 + k * 32 + qd * 8];
#pragma unroll
        for (int j = 0; j < 8; j++) {
            bf16x8 b = *(const bf16x8*)&Ws[(j * 16 + lr) * 136 + k * 32 + qd * 8];
            acc[j] = __builtin_amdgcn_mfma_f32_16x16x32_bf16(a, b, acc[j], 0, 0, 0);
        }
    }
    __syncthreads();   // all Xs/Ws reads done before overwrite

    // d1 -> Xs tile (shfl-packed u32)
#pragma unroll
    for (int r = 0; r < 4; r++) {
        int drow = w * 16 + qd * 4 + r;
#pragma unroll
        for (int j = 0; j < 8; j++) {
            int col = j * 16 + lr;
            float v = fmaxf(acc[j][r] + db1[col], 0.f);
            float vo = __shfl_xor(v, 1, 64);
            if ((lr & 1) == 0)
                *(unsigned*)&Xs[drow * 136 + j * 16 + lr] = pack2(v, vo);
        }
    }
#pragma unroll
    for (int r = 0; r < 4; r++) {
        int j = r * 256 + tid;
        int row = j >> 4, c8 = (j & 15) << 3;
        *(uint4*)&Ws[row * 136 + c8] = *(const uint4*)&wb_dw2[(size_t)row * 128 + c8];
    }
    __syncthreads();

    f32x4 acc2[4];
#pragma unroll
    for (int j = 0; j < 4; j++) acc2[j] = (f32x4){0.f, 0.f, 0.f, 0.f};
#pragma unroll
    for (int k = 0; k < 4; k++) {
        bf16x8 a = *(const bf16x8*)&Xs[(w * 16 + lr) * 136 + k * 32 + qd * 8];
#pragma unroll
        for (int j = 0; j < 4; j++) {
            bf16x8 b = *(const bf16x8*)&Ws[(j * 16 + lr) * 136 + k * 32 + qd * 8];
            acc2[j] = __builtin_amdgcn_mfma_f32_16x16x32_bf16(a, b, acc2[j], 0, 0, 0);
        }
    }
    float pr[4] = {0.f, 0.f, 0.f, 0.f};
#pragma unroll
    for (int j = 0; j < 4; j++) {
        int col = j * 16 + lr;
        float b = db2[col], wv = dw3[col];
#pragma unroll
        for (int r = 0; r < 4; r++) pr[r] += fmaxf(acc2[j][r] + b, 0.f) * wv;
    }
#pragma unroll
    for (int m = 1; m < 16; m <<= 1)
#pragma unroll
        for (int r = 0; r < 4; r++) pr[r] += __shfl_xor(pr[r], m, 64);
    if (lr == 0) {
        float b3 = db3[0];
#pragma unroll
        for (int r = 0; r < 4; r++) {
            int row = n0 + w * 16 + qd * 4 + r;
            if (row < N) {
                float prob = 1.f / (1.f + expf(-(pr[r] + b3)));
                fout[row] = (types[row] == 0) ? prob : 0.f;
            }
        }
    }
}

// ============ CSR build ========================================================
__global__ void hist_kernel(const int* __restrict__ ei, int E, int E2,
                            int* __restrict__ cnt, int* __restrict__ pos) {
    int e = blockIdx.x * blockDim.x + threadIdx.x;
    if (e >= E2) return;
    int d = (e < E) ? ei[E + e] : e - E;
    pos[e] = atomicAdd(&cnt[d], 1);
}

__global__ void scan1_kernel(const int* __restrict__ cnt, int* __restrict__ rs,
                             int* __restrict__ bsum, int N) {
    __shared__ int s[256];
    int i = blockIdx.x * 256 + threadIdx.x;
    int v = (i < N) ? cnt[i] : 0;
    s[threadIdx.x] = v;
    __syncthreads();
    for (int off = 1; off < 256; off <<= 1) {
        int t = (threadIdx.x >= off) ? s[threadIdx.x - off] : 0;
        __syncthreads();
        s[threadIdx.x] += t;
        __syncthreads();
    }
    if (i < N) rs[i] = s[threadIdx.x];
    if (threadIdx.x == 255) bsum[blockIdx.x] = s[255];
}

__global__ void scan23_kernel(int* __restrict__ rs, const int* __restrict__ cnt,
                              const int* __restrict__ bsum, int N) {
    __shared__ int sdata[256];
    int b = blockIdx.x;
    int partial = 0;
    for (int i = threadIdx.x; i < b; i += 256) partial += bsum[i];
    sdata[threadIdx.x] = partial;
    __syncthreads();
    for (int off = 128; off; off >>= 1) {
        if (threadIdx.x < off) sdata[threadIdx.x] += sdata[threadIdx.x + off];
        __syncthreads();
    }
    int pre = sdata[0];
    int i = b * 256 + threadIdx.x;
    if (i < N) rs[i] = rs[i] - cnt[i] + pre;
}

__global__ void scatter_kernel(const int* __restrict__ ei, int E, int E2,
                               const int* __restrict__ rs, const int* __restrict__ pos,
                               int* __restrict__ srclist) {
    int e = blockIdx.x * blockDim.x + threadIdx.x;
    if (e >= E2) return;
    int s, d;
    if (e < E) { s = ei[e]; d = ei[E + e]; }
    else       { s = d = e - E; }
    srclist[rs[d] + pos[e]] = s;
}

// ============ GAT aggregation with INLINE softmax =============================
// out[n] = (sum_e p_e * hl[src_e]) / (sum_e p_e),  p_e = exp(leaky(a_s+a_d))
// wave = node. lane l: edge-group g=l>>4, feature-chunk c=l&15 (8 bf16 = 16B),
// head = c>>2 (H=4). 12 edges per wave-step, 3 row loads in flight per lane.
// NOTE: `out` must NEVER alias `hl`.
template <int H>
__global__ __launch_bounds__(256) void gat_agg_kernel(
        const int* __restrict__ rs, const int* __restrict__ cnt,
        const int* __restrict__ srclist, const u16* __restrict__ hl,
        const float* __restrict__ a_s, const float* __restrict__ a_d,
        const float* __restrict__ bias, const u16* __restrict__ res,
        u16* __restrict__ out, int N) {
    int n = blockIdx.x * 4 + (threadIdx.x >> 6);
    int l = threadIdx.x & 63;
    if (n >= N) return;
    const int g = l >> 4;
    const int c = l & 15;
    const int head = (H == 1) ? 0 : (c >> 2);
    const int beg = rs[n];
    const int deg = cnt[n];
    const float ad = a_d[n * H + head];
    float acc0[8], acc1[8], acc2[8];
    float den0 = 0.f, den1 = 0.f, den2 = 0.f;
#pragma unroll
    for (int j = 0; j < 8; j++) { acc0[j] = 0.f; acc1[j] = 0.f; acc2[j] = 0.f; }

    for (int k = 0; k < deg; k += 12) {
        int i0 = k + g, i1 = k + 4 + g, i2 = k + 8 + g;
        int e0 = beg + min(i0, deg - 1);
        int e1 = beg + min(i1, deg - 1);
        int e2 = beg + min(i2, deg - 1);
        int s0 = srclist[e0], s1 = srclist[e1], s2 = srclist[e2];
        float al0 = a_s[s0 * H + head] + ad;
        float al1 = a_s[s1 * H + head] + ad;
        float al2 = a_s[s2 * H + head] + ad;
        al0 = (al0 > 0.f) ? al0 : NEG_SLOPE * al0;
        al1 = (al1 > 0.f) ? al1 : NEG_SLOPE * al1;
        al2 = (al2 > 0.f) ? al2 : NEG_SLOPE * al2;
        float p0 = __expf(fminf(al0, 80.f));
        float p1 = __expf(fminf(al1, 80.f));
        float p2 = __expf(fminf(al2, 80.f));
        if (i0 >= deg) p0 = 0.f;
        if (i1 >= deg) p1 = 0.f;
        if (i2 >= deg) p2 = 0.f;
        den0 += p0; den1 += p1; den2 += p2;
        uint4 v0 = *(const uint4*)&hl[(size_t)s0 * 128 + 8 * c];
        uint4 v1 = *(const uint4*)&hl[(size_t)s1 * 128 + 8 * c];
        uint4 v2 = *(const uint4*)&hl[(size_t)s2 * 128 + 8 * c];
        acc0[0] += p0 * lo16f(v0.x); acc0[1] += p0 * hi16f(v0.x);
        acc0[2] += p0 * lo16f(v0.y); acc0[3] += p0 * hi16f(v0.y);
        acc0[4] += p0 * lo16f(v0.z); acc0[5] += p0 * hi16f(v0.z);
        acc0[6] += p0 * lo16f(v0.w); acc0[7] += p0 * hi16f(v0.w);
        acc1[0] += p1 * lo16f(v1.x); acc1[1] += p1 * hi16f(v1.x);
        acc1[2] += p1 * lo16f(v1.y); acc1[3] += p1 * hi16f(v1.y);
        acc1[4] += p1 * lo16f(v1.z); acc1[5] += p1 * hi16f(v1.z);
        acc1[6] += p1 * lo16f(v1.w); acc1[7] += p1 * hi16f(v1.w);
        acc2[0] += p2 * lo16f(v2.x); acc2[1] += p2 * hi16f(v2.x);
        acc2[2] += p2 * lo16f(v2.y); acc2[3] += p2 * hi16f(v2.y);
        acc2[4] += p2 * lo16f(v2.z); acc2[5] += p2 * hi16f(v2.z);
        acc2[6] += p2 * lo16f(v2.w); acc2[7] += p2 * hi16f(v2.w);
    }
#pragma unroll
    for (int j = 0; j < 8; j++) {
        float a = acc0[j] + acc1[j] + acc2[j];
        a += __shfl_xor(a, 16, 64);
        a += __shfl_xor(a, 32, 64);
        acc0[j] = a;
    }
    float den = den0 + den1 + den2;
    den += __shfl_xor(den, 16, 64);
    den += __shfl_xor(den, 32, 64);
    if (g == 0) {
        float di = 1.f / den;   // deg >= 1 (self-loop)
        float4 b0 = *(const float4*)&bias[8 * c];
        float4 b1 = *(const float4*)&bias[8 * c + 4];
        float o[8];
        o[0] = fmaxf(acc0[0] * di + b0.x, 0.f);
        o[1] = fmaxf(acc0[1] * di + b0.y, 0.f);
        o[2] = fmaxf(acc0[2] * di + b0.z, 0.f);
        o[3] = fmaxf(acc0[3] * di + b0.w, 0.f);
        o[4] = fmaxf(acc0[4] * di + b1.x, 0.f);
        o[5] = fmaxf(acc0[5] * di + b1.y, 0.f);
        o[6] = fmaxf(acc0[6] * di + b1.z, 0.f);
        o[7] = fmaxf(acc0[7] * di + b1.w, 0.f);
        if (res) {
            uint4 rv = *(const uint4*)&res[(size_t)n * 128 + 8 * c];
            o[0] += lo16f(rv.x); o[1] += hi16f(rv.x);
            o[2] += lo16f(rv.y); o[3] += hi16f(rv.y);
            o[4] += lo16f(rv.z); o[5] += hi16f(rv.z);
            o[6] += lo16f(rv.w); o[7] += hi16f(rv.w);
        }
        uint4 ov = make_uint4(pack2(o[0], o[1]), pack2(o[2], o[3]),
                              pack2(o[4], o[5]), pack2(o[6], o[7]));
        *(uint4*)&out[(size_t)n * 128 + 8 * c] = ov;
    }
}

extern "C" void kernel_launch(void* const* d_in, const int* in_sizes, int n_in,
                              void* d_out, int out_size, void* d_ws, size_t ws_size,
                              hipStream_t stream) {
    const float* x     = (const float*)d_in[0];
    const int*   types = (const int*)d_in[1];
    const int*   ei    = (const int*)d_in[2];   // int64 in reference -> int32 on device
    const float* ew1 = (const float*)d_in[3];
    const float* eb1 = (const float*)d_in[4];
    const float* ew2 = (const float*)d_in[5];
    const float* eb2 = (const float*)d_in[6];
    const float* cw1 = (const float*)d_in[7];
    const float* cb1 = (const float*)d_in[8];
    const float* cw2 = (const float*)d_in[9];
    const float* cb2 = (const float*)d_in[10];
    const float* lin0 = (const float*)d_in[11];
    const float* as0  = (const float*)d_in[12];
    const float* ad0  = (const float*)d_in[13];
    const float* b0   = (const float*)d_in[14];
    const float* lin1 = (const float*)d_in[15];
    const float* as1  = (const float*)d_in[16];
    const float* ad1  = (const float*)d_in[17];
    const float* b1   = (const float*)d_in[18];
    const float* lin2 = (const float*)d_in[19];
    const float* as2  = (const float*)d_in[20];
    const float* ad2  = (const float*)d_in[21];
    const float* b2   = (const float*)d_in[22];
    const float* dw1 = (const float*)d_in[23];
    const float* db1 = (const float*)d_in[24];
    const float* dw2 = (const float*)d_in[25];
    const float* db2 = (const float*)d_in[26];
    const float* dw3 = (const float*)d_in[27];
    const float* db3 = (const float*)d_in[28];

    int N  = in_sizes[1];
    int E  = in_sizes[2] / 2;
    int E2 = E + N;

    size_t NF = (size_t)N * HIDDEN;
    u16* bufA = (u16*)d_ws;
    u16* bufB = bufA + NF;
    u16* bufC = bufB + NF;
    float* a_s  = (float*)(bufC + NF);
    float* a_d  = a_s + (size_t)N * 4;
    int* rs      = (int*)(a_d + (size_t)N * 4);
    int* cnt     = rs + N;
    int* pos     = cnt + N;             // E2 entries
    int* bsum    = pos + E2;            // up to 1024 entries
    int* srclist = bsum + 1024;         // E2 entries
    u16* wb      = (u16*)(srclist + E2);  // 106496 bf16 pre-converted weights
    u16* wb_ew2  = wb;
    u16* wb_cw2  = wb + 16384;
    u16* wb_lin0 = wb + 32768;
    u16* wb_lin1 = wb + 49152;
    u16* wb_lin2 = wb + 65536;
    u16* wb_dw1  = wb + 81920;
    u16* wb_dw2  = wb + 98304;

    int nb = (N + 255) / 256;

    // ---- weight pre-convert + cnt zero
    WPtrs wp;
    wp.p[0] = ew2; wp.p[1] = cw2; wp.p[2] = lin0; wp.p[3] = lin1;
    wp.p[4] = lin2; wp.p[5] = dw1; wp.p[6] = dw2;
    int cz = max(N, 53248);
    convw_zero_kernel<<<(cz + 255) / 256, 256, 0, stream>>>(wp, (unsigned*)wb, 53248,
                                                            cnt, N);

    // ---- CSR build
    hist_kernel<<<(E2 + 255) / 256, 256, 0, stream>>>(ei, E, E2, cnt, pos);
    scan1_kernel<<<nb, 256, 0, stream>>>(cnt, rs, bsum, N);
    scan23_kernel<<<nb, 256, 0, stream>>>(rs, cnt, bsum, N);
    scatter_kernel<<<(E2 + 255) / 256, 256, 0, stream>>>(ei, E, E2, rs, pos, srclist);

    int gx = (N + 63) / 64;

    // ---- encoder -> bufA (h)
    encoder_kernel<<<gx, 256, 0, stream>>>(x, types, ew1, eb1, cw1, cb1,
                                           wb_ew2, wb_cw2, eb2, cb2, bufA, N);

    // ---- layer 0: hl -> bufB ; h0 = relu(gat) -> bufA
    gemm_hl_kernel<4><<<gx, 256, 0, stream>>>(bufA, wb_lin0, as0, ad0,
                                              bufB, a_s, a_d, N);
    gat_agg_kernel<4><<<(N + 3) / 4, 256, 0, stream>>>(rs, cnt, srclist, bufB,
                                                       a_s, a_d, b0, nullptr, bufA, N);
    // ---- layer 1: hl -> bufB ; h1 = h0 + relu(gat) -> bufC
    gemm_hl_kernel<4><<<gx, 256, 0, stream>>>(bufA, wb_lin1, as1, ad1,
                                              bufB, a_s, a_d, N);
    gat_agg_kernel<4><<<(N + 3) / 4, 256, 0, stream>>>(rs, cnt, srclist, bufB,
                                                       a_s, a_d, b1, bufA, bufC, N);
    // ---- layer 2 (1 head): hl -> bufB ; h2 = h1 + relu(gat) -> bufA
    gemm_hl_kernel<1><<<gx, 256, 0, stream>>>(bufC, wb_lin2, as2, ad2,
                                              bufB, a_s, a_d, N);
    gat_agg_kernel<1><<<(N + 3) / 4, 256, 0, stream>>>(rs, cnt, srclist, bufB,
                                                       a_s, a_d, b2, bufC, bufA, N);

    // ---- fused decoder: bufA -> d_out
    dec_kernel<<<gx, 256, 0, stream>>>(bufA, types, wb_dw1, db1, wb_dw2, db2,
                                       dw3, db3, (float*)d_out, N);
}

// Round 19
// 455.585 us; speedup vs baseline: 1.0317x; 1.0317x over previous
//
#include <hip/hip_runtime.h>
#include <math.h>

#define HIDDEN 128
#define NEG_SLOPE 0.2f

typedef unsigned short u16;
typedef __attribute__((ext_vector_type(8))) short bf16x8;
typedef __attribute__((ext_vector_type(4))) float f32x4;

__device__ __forceinline__ u16 f2bf(float f) {
    unsigned u = __float_as_uint(f);
    unsigned r = (u + 0x7FFFu + ((u >> 16) & 1u)) >> 16;   // round-nearest-even
    return (u16)r;
}
__device__ __forceinline__ float bf2f(u16 u) {
    return __uint_as_float((unsigned)u << 16);
}
__device__ __forceinline__ unsigned pack2(float a, float b) {
    return (unsigned)f2bf(a) | ((unsigned)f2bf(b) << 16);
}
__device__ __forceinline__ float lo16f(unsigned v) { return bf2f((u16)v); }
__device__ __forceinline__ float hi16f(unsigned v) { return bf2f((u16)(v >> 16)); }

// ============ fp32->bf16 weight conversion + cnt zeroing (one dispatch) =======
struct WPtrs { const float* p[7]; };
__global__ void convw_zero_kernel(WPtrs wp, unsigned* __restrict__ wb, int totalPairs,
                                  int* __restrict__ cnt, int N) {
    int i = blockIdx.x * blockDim.x + threadIdx.x;
    if (i < N) cnt[i] = 0;
    if (i < totalPairs) {
        int e = i * 2;
        int seg, off;
        if (e < 98304) { seg = e >> 14; off = e & 16383; }
        else           { seg = 6;       off = e - 98304; }
        const float* s = wp.p[seg];
        wb[i] = pack2(s[off], s[off + 1]);
    }
}

// ============ encoder (+ co-scheduled hist in extra blocks) ===================
// Blocks [0,encBlocks): encoder (A-frags in registers, two weight passes).
// Blocks [encBlocks,..): edge histogram (independent work, rides the dispatch).
__global__ __launch_bounds__(256) void enc_hist_kernel(
        const float* __restrict__ x, const int* __restrict__ types,
        const float* __restrict__ ew1, const float* __restrict__ eb1,
        const float* __restrict__ cw1, const float* __restrict__ cb1,
        const u16* __restrict__ wb_ew2, const u16* __restrict__ wb_cw2,
        const float* __restrict__ eb2, const float* __restrict__ cb2,
        u16* __restrict__ out, int N, int encBlocks,
        const int* __restrict__ ei, int E, int E2,
        int* __restrict__ cnt, int* __restrict__ pos) {
    if ((int)blockIdx.x >= encBlocks) {
        int e = (blockIdx.x - encBlocks) * 256 + threadIdx.x;
        if (e < E2) {
            int d = (e < E) ? ei[E + e] : e - E;
            pos[e] = atomicAdd(&cnt[d], 1);
        }
        return;
    }
    __shared__ u16 Ws[128 * 136];
    __shared__ float xsh[128];
    __shared__ float w1sh[640];   // ew1(256) eb1(128) cw1(128) cb1(128)
    const int tid = threadIdx.x;
    const int n0 = blockIdx.x * 64;

    if (tid < 128) {
        int n = n0 + (tid >> 1);
        xsh[tid] = (n < N) ? x[2 * n + (tid & 1)] : 0.f;
    }
    if (tid < 256) w1sh[tid] = ew1[tid];
    if (tid < 128) { w1sh[256 + tid] = eb1[tid]; w1sh[384 + tid] = cw1[tid];
                     w1sh[512 + tid] = cb1[tid]; }
#pragma unroll
    for (int r = 0; r < 8; r++) {
        int j = r * 256 + tid;
        int row = j >> 4, c8 = (j & 15) << 3;
        *(uint4*)&Ws[row * 136 + c8] = *(const uint4*)&wb_ew2[(size_t)row * 128 + c8];
    }
    __syncthreads();

    const int w = tid >> 6, lane = tid & 63;
    const int qd = lane >> 4, lr = lane & 15;
    const int arow = w * 16 + lr;
    const float x0 = xsh[2 * arow], x1 = xsh[2 * arow + 1];

    f32x4 acc_i[8], acc_c[8];
#pragma unroll
    for (int j = 0; j < 8; j++) acc_i[j] = (f32x4){0.f, 0.f, 0.f, 0.f};

#pragma unroll
    for (int k = 0; k < 4; k++) {
        bf16x8 a;
#pragma unroll
        for (int j = 0; j < 8; j++) {
            int t = k * 32 + qd * 8 + j;
            float v = fmaxf(w1sh[2 * t] * x0 + w1sh[2 * t + 1] * x1 + w1sh[256 + t], 0.f);
            a[j] = (short)f2bf(v);
        }
#pragma unroll
        for (int j = 0; j < 8; j++) {
            bf16x8 b = *(const bf16x8*)&Ws[(j * 16 + lr) * 136 + k * 32 + qd * 8];
            acc_i[j] = __builtin_amdgcn_mfma_f32_16x16x32_bf16(a, b, acc_i[j], 0, 0, 0);
        }
    }
    __syncthreads();

#pragma unroll
    for (int r = 0; r < 8; r++) {
        int j = r * 256 + tid;
        int rw = j >> 4, c8 = (j & 15) << 3;
        *(uint4*)&Ws[rw * 136 + c8] = *(const uint4*)&wb_cw2[(size_t)rw * 128 + c8];
    }
    __syncthreads();

#pragma unroll
    for (int j = 0; j < 8; j++) acc_c[j] = (f32x4){0.f, 0.f, 0.f, 0.f};
#pragma unroll
    for (int k = 0; k < 4; k++) {
        bf16x8 a;
#pragma unroll
        for (int j = 0; j < 8; j++) {
            int t = k * 32 + qd * 8 + j;
            float v = fmaxf(w1sh[384 + t] * x0 + w1sh[512 + t], 0.f);
            a[j] = (short)f2bf(v);
        }
#pragma unroll
        for (int j = 0; j < 8; j++) {
            bf16x8 b = *(const bf16x8*)&Ws[(j * 16 + lr) * 136 + k * 32 + qd * 8];
            acc_c[j] = __builtin_amdgcn_mfma_f32_16x16x32_bf16(a, b, acc_c[j], 0, 0, 0);
        }
    }

#pragma unroll
    for (int r = 0; r < 4; r++) {
        int orow = n0 + w * 16 + qd * 4 + r;
        if (orow >= N) continue;
        int ty = types[orow];
#pragma unroll
        for (int j = 0; j < 8; j++) {
            int col = j * 16 + lr;
            float v;
            if (ty == 0)      v = fmaxf(acc_i[j][r] + eb2[col], 0.f);
            else if (ty == 1) v = fmaxf(acc_c[j][r] + cb2[col], 0.f);
            else              v = 0.f;
            out[(size_t)orow * HIDDEN + col] = f2bf(v);
        }
    }
}

// ============ hl GEMM (+ optional co-scheduled scan1 in extra blocks) =========
// Blocks [0,gemmBlocks): X @ lin^T + attention dots -> hl, a_s, a_d.
// Blocks [gemmBlocks,..): scan1 (per-chunk inclusive scan of cnt -> rs, bsum).
template <int DH>
__global__ __launch_bounds__(256) void gemm_hl_kernel(
        const u16* __restrict__ X, const u16* __restrict__ Wb,
        const float* __restrict__ att_s, const float* __restrict__ att_d,
        u16* __restrict__ hl, float* __restrict__ a_s, float* __restrict__ a_d,
        int N, int gemmBlocks,
        const int* __restrict__ cnt, int* __restrict__ rs, int* __restrict__ bsum) {
    __shared__ u16 Xs[64 * 136];
    __shared__ u16 Ws[128 * 136];
    const int tid = threadIdx.x;

    if ((int)blockIdx.x >= gemmBlocks) {
        // scan1 body (chunk = blockIdx.x - gemmBlocks)
        int* s = (int*)Xs;   // reuse LDS
        int chunk = blockIdx.x - gemmBlocks;
        int i = chunk * 256 + tid;
        int v = (i < N) ? cnt[i] : 0;
        s[tid] = v;
        __syncthreads();
        for (int off = 1; off < 256; off <<= 1) {
            int t = (tid >= off) ? s[tid - off] : 0;
            __syncthreads();
            s[tid] += t;
            __syncthreads();
        }
        if (i < N) rs[i] = s[tid];
        if (tid == 255) bsum[chunk] = s[255];
        return;
    }

    const int n0 = blockIdx.x * 64;
#pragma unroll
    for (int r = 0; r < 4; r++) {
        int j = r * 256 + tid;
        int row = j >> 4, c8 = (j & 15) << 3;
        int n = n0 + row;
        uint4 v = make_uint4(0u, 0u, 0u, 0u);
        if (n < N) v = *(const uint4*)&X[(size_t)n * 128 + c8];
        *(uint4*)&Xs[row * 136 + c8] = v;
    }
#pragma unroll
    for (int r = 0; r < 8; r++) {
        int j = r * 256 + tid;
        int row = j >> 4, c8 = (j & 15) << 3;
        *(uint4*)&Ws[row * 136 + c8] = *(const uint4*)&Wb[(size_t)row * 128 + c8];
    }
    __syncthreads();

    const int w = tid >> 6, lane = tid & 63;
    const int qd = lane >> 4, lr = lane & 15;

    f32x4 acc[8];
#pragma unroll
    for (int j = 0; j < 8; j++) acc[j] = (f32x4){0.f, 0.f, 0.f, 0.f};
#pragma unroll
    for (int k = 0; k < 4; k++) {
        bf16x8 a = *(const bf16x8*)&Xs[(w * 16 + lr) * 136 + k * 32 + qd * 8];
#pragma unroll
        for (int j = 0; j < 8; j++) {
            bf16x8 b = *(const bf16x8*)&Ws[(j * 16 + lr) * 136 + k * 32 + qd * 8];
            acc[j] = __builtin_amdgcn_mfma_f32_16x16x32_bf16(a, b, acc[j], 0, 0, 0);
        }
    }

    constexpr int NH = (DH == 4) ? 4 : 1;
    float sp[NH][4], dp[NH][4];
#pragma unroll
    for (int h = 0; h < NH; h++)
#pragma unroll
        for (int r = 0; r < 4; r++) { sp[h][r] = 0.f; dp[h][r] = 0.f; }
#pragma unroll
    for (int j = 0; j < 8; j++) {
        int col = j * 16 + lr;
        float as_ = att_s[col], ad_ = att_d[col];
        int h = (DH == 4) ? (j >> 1) : 0;
#pragma unroll
        for (int r = 0; r < 4; r++) {
            sp[h][r] += acc[j][r] * as_;
            dp[h][r] += acc[j][r] * ad_;
        }
    }
#pragma unroll
    for (int m = 1; m < 16; m <<= 1)
#pragma unroll
        for (int h = 0; h < NH; h++)
#pragma unroll
            for (int r = 0; r < 4; r++) {
                sp[h][r] += __shfl_xor(sp[h][r], m, 64);
                dp[h][r] += __shfl_xor(dp[h][r], m, 64);
            }
    if (lr == 0) {
#pragma unroll
        for (int r = 0; r < 4; r++) {
            int row = n0 + w * 16 + qd * 4 + r;
            if (row < N) {
#pragma unroll
                for (int h = 0; h < NH; h++) {
                    a_s[row * DH + h] = sp[h][r];
                    a_d[row * DH + h] = dp[h][r];
                }
            }
        }
    }
#pragma unroll
    for (int r = 0; r < 4; r++) {
        int row = n0 + w * 16 + qd * 4 + r;
        if (row >= N) continue;
#pragma unroll
        for (int j = 0; j < 8; j++)
            hl[(size_t)row * 128 + j * 16 + lr] = f2bf(acc[j][r]);
    }
}

// ============ FUSED decoder: d1 GEMM -> d2 GEMM -> dot/sigmoid/mask ===========
__global__ __launch_bounds__(256) void dec_kernel(
        const u16* __restrict__ X, const int* __restrict__ types,
        const u16* __restrict__ wb_dw1, const float* __restrict__ db1,
        const u16* __restrict__ wb_dw2, const float* __restrict__ db2,
        const float* __restrict__ dw3, const float* __restrict__ db3,
        float* __restrict__ fout, int N) {
    __shared__ u16 Xs[64 * 136];
    __shared__ u16 Ws[128 * 136];
    const int tid = threadIdx.x;
    const int n0 = blockIdx.x * 64;

#pragma unroll
    for (int r = 0; r < 4; r++) {
        int j = r * 256 + tid;
        int row = j >> 4, c8 = (j & 15) << 3;
        int n = n0 + row;
        uint4 v = make_uint4(0u, 0u, 0u, 0u);
        if (n < N) v = *(const uint4*)&X[(size_t)n * 128 + c8];
        *(uint4*)&Xs[row * 136 + c8] = v;
    }
#pragma unroll
    for (int r = 0; r < 8; r++) {
        int j = r * 256 + tid;
        int row = j >> 4, c8 = (j & 15) << 3;
        *(uint4*)&Ws[row * 136 + c8] = *(const uint4*)&wb_dw1[(size_t)row * 128 + c8];
    }
    __syncthreads();

    const int w = tid >> 6, lane = tid & 63;
    const int qd = lane >> 4, lr = lane & 15;

    f32x4 acc[8];
#pragma unroll
    for (int j = 0; j < 8; j++) acc[j] = (f32x4){0.f, 0.f, 0.f, 0.f};
#pragma unroll
    for (int k = 0; k < 4; k++) {
        bf16x8 a = *(const bf16x8*)&Xs[(w * 16 + lr) * 136 + k * 32 + qd * 8];
#pragma unroll
        for (int j = 0; j < 8; j++) {
            bf16x8 b = *(const bf16x8*)&Ws[(j * 16 + lr) * 136 + k * 32 + qd * 8];
            acc[j] = __builtin_amdgcn_mfma_f32_16x16x32_bf16(a, b, acc[j], 0, 0, 0);
        }
    }
    __syncthreads();   // all Xs/Ws reads done before overwrite

    // d1 -> Xs tile (shfl-packed u32)
#pragma unroll
    for (int r = 0; r < 4; r++) {
        int drow = w * 16 + qd * 4 + r;
#pragma unroll
        for (int j = 0; j < 8; j++) {
            int col = j * 16 + lr;
            float v = fmaxf(acc[j][r] + db1[col], 0.f);
            float vo = __shfl_xor(v, 1, 64);
            if ((lr & 1) == 0)
                *(unsigned*)&Xs[drow * 136 + j * 16 + lr] = pack2(v, vo);
        }
    }
#pragma unroll
    for (int r = 0; r < 4; r++) {
        int j = r * 256 + tid;
        int row = j >> 4, c8 = (j & 15) << 3;
        *(uint4*)&Ws[row * 136 + c8] = *(const uint4*)&wb_dw2[(size_t)row * 128 + c8];
    }
    __syncthreads();

    f32x4 acc2[4];
#pragma unroll
    for (int j = 0; j < 4; j++) acc2[j] = (f32x4){0.f, 0.f, 0.f, 0.f};
#pragma unroll
    for (int k = 0; k < 4; k++) {
        bf16x8 a = *(const bf16x8*)&Xs[(w * 16 + lr) * 136 + k * 32 + qd * 8];
#pragma unroll
        for (int j = 0; j < 4; j++) {
            bf16x8 b = *(const bf16x8*)&Ws[(j * 16 + lr) * 136 + k * 32 + qd * 8];
            acc2[j] = __builtin_amdgcn_mfma_f32_16x16x32_bf16(a, b, acc2[j], 0, 0, 0);
        }
    }
    float pr[4] = {0.f, 0.f, 0.f, 0.f};
#pragma unroll
    for (int j = 0; j < 4; j++) {
        int col = j * 16 + lr;
        float b = db2[col], wv = dw3[col];
#pragma unroll
        for (int r = 0; r < 4; r++) pr[r] += fmaxf(acc2[j][r] + b, 0.f) * wv;
    }
#pragma unroll
    for (int m = 1; m < 16; m <<= 1)
#pragma unroll
        for (int r = 0; r < 4; r++) pr[r] += __shfl_xor(pr[r], m, 64);
    if (lr == 0) {
        float b3 = db3[0];
#pragma unroll
        for (int r = 0; r < 4; r++) {
            int row = n0 + w * 16 + qd * 4 + r;
            if (row < N) {
                float prob = 1.f / (1.f + expf(-(pr[r] + b3)));
                fout[row] = (types[row] == 0) ? prob : 0.f;
            }
        }
    }
}

// ============ CSR build (remaining serial steps) ==============================
__global__ void scan23_kernel(int* __restrict__ rs, const int* __restrict__ cnt,
                              const int* __restrict__ bsum, int N) {
    __shared__ int sdata[256];
    int b = blockIdx.x;
    int partial = 0;
    for (int i = threadIdx.x; i < b; i += 256) partial += bsum[i];
    sdata[threadIdx.x] = partial;
    __syncthreads();
    for (int off = 128; off; off >>= 1) {
        if (threadIdx.x < off) sdata[threadIdx.x] += sdata[threadIdx.x + off];
        __syncthreads();
    }
    int pre = sdata[0];
    int i = b * 256 + threadIdx.x;
    if (i < N) rs[i] = rs[i] - cnt[i] + pre;
}

__global__ void scatter_kernel(const int* __restrict__ ei, int E, int E2,
                               const int* __restrict__ rs, const int* __restrict__ pos,
                               int* __restrict__ srclist) {
    int e = blockIdx.x * blockDim.x + threadIdx.x;
    if (e >= E2) return;
    int s, d;
    if (e < E) { s = ei[e]; d = ei[E + e]; }
    else       { s = d = e - E; }
    srclist[rs[d] + pos[e]] = s;
}

// ============ GAT aggregation with INLINE softmax =============================
// out[n] = (sum_e p_e * hl[src_e]) / (sum_e p_e),  p_e = exp(leaky(a_s+a_d))
// wave = node. lane l: edge-group g=l>>4, feature-chunk c=l&15 (8 bf16 = 16B),
// head = c>>2 (H=4). 12 edges per wave-step, 3 row loads in flight per lane.
// NOTE: `out` must NEVER alias `hl`.
template <int H>
__global__ __launch_bounds__(256) void gat_agg_kernel(
        const int* __restrict__ rs, const int* __restrict__ cnt,
        const int* __restrict__ srclist, const u16* __restrict__ hl,
        const float* __restrict__ a_s, const float* __restrict__ a_d,
        const float* __restrict__ bias, const u16* __restrict__ res,
        u16* __restrict__ out, int N) {
    int n = blockIdx.x * 4 + (threadIdx.x >> 6);
    int l = threadIdx.x & 63;
    if (n >= N) return;
    const int g = l >> 4;
    const int c = l & 15;
    const int head = (H == 1) ? 0 : (c >> 2);
    const int beg = rs[n];
    const int deg = cnt[n];
    const float ad = a_d[n * H + head];
    float acc0[8], acc1[8], acc2[8];
    float den0 = 0.f, den1 = 0.f, den2 = 0.f;
#pragma unroll
    for (int j = 0; j < 8; j++) { acc0[j] = 0.f; acc1[j] = 0.f; acc2[j] = 0.f; }

    for (int k = 0; k < deg; k += 12) {
        int i0 = k + g, i1 = k + 4 + g, i2 = k + 8 + g;
        int e0 = beg + min(i0, deg - 1);
        int e1 = beg + min(i1, deg - 1);
        int e2 = beg + min(i2, deg - 1);
        int s0 = srclist[e0], s1 = srclist[e1], s2 = srclist[e2];
        float al0 = a_s[s0 * H + head] + ad;
        float al1 = a_s[s1 * H + head] + ad;
        float al2 = a_s[s2 * H + head] + ad;
        al0 = (al0 > 0.f) ? al0 : NEG_SLOPE * al0;
        al1 = (al1 > 0.f) ? al1 : NEG_SLOPE * al1;
        al2 = (al2 > 0.f) ? al2 : NEG_SLOPE * al2;
        float p0 = __expf(fminf(al0, 80.f));
        float p1 = __expf(fminf(al1, 80.f));
        float p2 = __expf(fminf(al2, 80.f));
        if (i0 >= deg) p0 = 0.f;
        if (i1 >= deg) p1 = 0.f;
        if (i2 >= deg) p2 = 0.f;
        den0 += p0; den1 += p1; den2 += p2;
        uint4 v0 = *(const uint4*)&hl[(size_t)s0 * 128 + 8 * c];
        uint4 v1 = *(const uint4*)&hl[(size_t)s1 * 128 + 8 * c];
        uint4 v2 = *(const uint4*)&hl[(size_t)s2 * 128 + 8 * c];
        acc0[0] += p0 * lo16f(v0.x); acc0[1] += p0 * hi16f(v0.x);
        acc0[2] += p0 * lo16f(v0.y); acc0[3] += p0 * hi16f(v0.y);
        acc0[4] += p0 * lo16f(v0.z); acc0[5] += p0 * hi16f(v0.z);
        acc0[6] += p0 * lo16f(v0.w); acc0[7] += p0 * hi16f(v0.w);
        acc1[0] += p1 * lo16f(v1.x); acc1[1] += p1 * hi16f(v1.x);
        acc1[2] += p1 * lo16f(v1.y); acc1[3] += p1 * hi16f(v1.y);
        acc1[4] += p1 * lo16f(v1.z); acc1[5] += p1 * hi16f(v1.z);
        acc1[6] += p1 * lo16f(v1.w); acc1[7] += p1 * hi16f(v1.w);
        acc2[0] += p2 * lo16f(v2.x); acc2[1] += p2 * hi16f(v2.x);
        acc2[2] += p2 * lo16f(v2.y); acc2[3] += p2 * hi16f(v2.y);
        acc2[4] += p2 * lo16f(v2.z); acc2[5] += p2 * hi16f(v2.z);
        acc2[6] += p2 * lo16f(v2.w); acc2[7] += p2 * hi16f(v2.w);
    }
#pragma unroll
    for (int j = 0; j < 8; j++) {
        float a = acc0[j] + acc1[j] + acc2[j];
        a += __shfl_xor(a, 16, 64);
        a += __shfl_xor(a, 32, 64);
        acc0[j] = a;
    }
    float den = den0 + den1 + den2;
    den += __shfl_xor(den, 16, 64);
    den += __shfl_xor(den, 32, 64);
    if (g == 0) {
        float di = 1.f / den;   // deg >= 1 (self-loop)
        float4 b0 = *(const float4*)&bias[8 * c];
        float4 b1 = *(const float4*)&bias[8 * c + 4];
        float o[8];
        o[0] = fmaxf(acc0[0] * di + b0.x, 0.f);
        o[1] = fmaxf(acc0[1] * di + b0.y, 0.f);
        o[2] = fmaxf(acc0[2] * di + b0.z, 0.f);
        o[3] = fmaxf(acc0[3] * di + b0.w, 0.f);
        o[4] = fmaxf(acc0[4] * di + b1.x, 0.f);
        o[5] = fmaxf(acc0[5] * di + b1.y, 0.f);
        o[6] = fmaxf(acc0[6] * di + b1.z, 0.f);
        o[7] = fmaxf(acc0[7] * di + b1.w, 0.f);
        if (res) {
            uint4 rv = *(const uint4*)&res[(size_t)n * 128 + 8 * c];
            o[0] += lo16f(rv.x); o[1] += hi16f(rv.x);
            o[2] += lo16f(rv.y); o[3] += hi16f(rv.y);
            o[4] += lo16f(rv.z); o[5] += hi16f(rv.z);
            o[6] += lo16f(rv.w); o[7] += hi16f(rv.w);
        }
        uint4 ov = make_uint4(pack2(o[0], o[1]), pack2(o[2], o[3]),
                              pack2(o[4], o[5]), pack2(o[6], o[7]));
        *(uint4*)&out[(size_t)n * 128 + 8 * c] = ov;
    }
}

extern "C" void kernel_launch(void* const* d_in, const int* in_sizes, int n_in,
                              void* d_out, int out_size, void* d_ws, size_t ws_size,
                              hipStream_t stream) {
    const float* x     = (const float*)d_in[0];
    const int*   types = (const int*)d_in[1];
    const int*   ei    = (const int*)d_in[2];   // int64 in reference -> int32 on device
    const float* ew1 = (const float*)d_in[3];
    const float* eb1 = (const float*)d_in[4];
    const float* ew2 = (const float*)d_in[5];
    const float* eb2 = (const float*)d_in[6];
    const float* cw1 = (const float*)d_in[7];
    const float* cb1 = (const float*)d_in[8];
    const float* cw2 = (const float*)d_in[9];
    const float* cb2 = (const float*)d_in[10];
    const float* lin0 = (const float*)d_in[11];
    const float* as0  = (const float*)d_in[12];
    const float* ad0  = (const float*)d_in[13];
    const float* b0   = (const float*)d_in[14];
    const float* lin1 = (const float*)d_in[15];
    const float* as1  = (const float*)d_in[16];
    const float* ad1  = (const float*)d_in[17];
    const float* b1   = (const float*)d_in[18];
    const float* lin2 = (const float*)d_in[19];
    const float* as2  = (const float*)d_in[20];
    const float* ad2  = (const float*)d_in[21];
    const float* b2   = (const float*)d_in[22];
    const float* dw1 = (const float*)d_in[23];
    const float* db1 = (const float*)d_in[24];
    const float* dw2 = (const float*)d_in[25];
    const float* db2 = (const float*)d_in[26];
    const float* dw3 = (const float*)d_in[27];
    const float* db3 = (const float*)d_in[28];

    int N  = in_sizes[1];
    int E  = in_sizes[2] / 2;
    int E2 = E + N;

    size_t NF = (size_t)N * HIDDEN;
    u16* bufA = (u16*)d_ws;
    u16* bufB = bufA + NF;
    u16* bufC = bufB + NF;
    float* a_s  = (float*)(bufC + NF);
    float* a_d  = a_s + (size_t)N * 4;
    int* rs      = (int*)(a_d + (size_t)N * 4);
    int* cnt     = rs + N;
    int* pos     = cnt + N;             // E2 entries
    int* bsum    = pos + E2;            // up to 1024 entries
    int* srclist = bsum + 1024;         // E2 entries
    u16* wb      = (u16*)(srclist + E2);  // 106496 bf16 pre-converted weights
    u16* wb_ew2  = wb;
    u16* wb_cw2  = wb + 16384;
    u16* wb_lin0 = wb + 32768;
    u16* wb_lin1 = wb + 49152;
    u16* wb_lin2 = wb + 65536;
    u16* wb_dw1  = wb + 81920;
    u16* wb_dw2  = wb + 98304;

    int nb = (N + 255) / 256;
    int hb = (E2 + 255) / 256;
    int gx = (N + 63) / 64;

    // ---- D1: weight pre-convert + cnt zero
    WPtrs wp;
    wp.p[0] = ew2; wp.p[1] = cw2; wp.p[2] = lin0; wp.p[3] = lin1;
    wp.p[4] = lin2; wp.p[5] = dw1; wp.p[6] = dw2;
    int cz = max(N, 53248);
    convw_zero_kernel<<<(cz + 255) / 256, 256, 0, stream>>>(wp, (unsigned*)wb, 53248,
                                                            cnt, N);

    // ---- D2: encoder (+ co-scheduled hist) -> bufA, cnt, pos
    enc_hist_kernel<<<gx + hb, 256, 0, stream>>>(x, types, ew1, eb1, cw1, cb1,
                                                 wb_ew2, wb_cw2, eb2, cb2, bufA, N,
                                                 gx, ei, E, E2, cnt, pos);

    // ---- D3: layer-0 hl GEMM (+ co-scheduled scan1) -> bufB, a_s, a_d, rs, bsum
    gemm_hl_kernel<4><<<gx + nb, 256, 0, stream>>>(bufA, wb_lin0, as0, ad0,
                                                   bufB, a_s, a_d, N, gx,
                                                   cnt, rs, bsum);
    // ---- D4/D5: finish CSR
    scan23_kernel<<<nb, 256, 0, stream>>>(rs, cnt, bsum, N);
    scatter_kernel<<<hb, 256, 0, stream>>>(ei, E, E2, rs, pos, srclist);

    // ---- D6: layer-0 aggregate: h0 -> bufA
    gat_agg_kernel<4><<<(N + 3) / 4, 256, 0, stream>>>(rs, cnt, srclist, bufB,
                                                       a_s, a_d, b0, nullptr, bufA, N);
    // ---- D7/D8: layer 1
    gemm_hl_kernel<4><<<gx, 256, 0, stream>>>(bufA, wb_lin1, as1, ad1,
                                              bufB, a_s, a_d, N, gx,
                                              nullptr, nullptr, nullptr);
    gat_agg_kernel<4><<<(N + 3) / 4, 256, 0, stream>>>(rs, cnt, srclist, bufB,
                                                       a_s, a_d, b1, bufA, bufC, N);
    // ---- D9/D10: layer 2 (1 head)
    gemm_hl_kernel<1><<<gx, 256, 0, stream>>>(bufC, wb_lin2, as2, ad2,
                                              bufB, a_s, a_d, N, gx,
                                              nullptr, nullptr, nullptr);
    gat_agg_kernel<1><<<(N + 3) / 4, 256, 0, stream>>>(rs, cnt, srclist, bufB,
                                                       a_s, a_d, b2, bufC, bufA, N);

    // ---- D11: fused decoder: bufA -> d_out
    dec_kernel<<<gx, 256, 0, stream>>>(bufA, types, wb_dw1, db1, wb_dw2, db2,
                                       dw3, db3, (float*)d_out, N);
}